// Round 12
// baseline (2512.478 us; speedup 1.0000x reference)
//
#include <hip/hip_runtime.h>
#include <math.h>

#define BATCH 512
#define TSEQ  256
#define HID   512
#define G4    2048
#define DECSTEPS 42
#define CPS 65
#define CPH (64*CPS)

typedef __attribute__((ext_vector_type(8))) _Float16 half8;
typedef __attribute__((ext_vector_type(16))) float f32x16;
typedef __attribute__((ext_vector_type(2))) unsigned long long u64x2;
typedef unsigned short u16;
typedef unsigned int u32;
typedef unsigned long long u64;

__device__ __forceinline__ float sigf(float x){ return __builtin_amdgcn_rcpf(1.0f + __expf(-x)); }
__device__ __forceinline__ float tanhf_fast(float x){ return 2.0f*__builtin_amdgcn_rcpf(1.0f + __expf(-2.0f*x)) - 1.0f; }

// Whh fp32 -> fp16 plane
__global__ __launch_bounds__(256) void pack_w(const float* __restrict__ W, u16* __restrict__ P){
    int i = (blockIdx.x*256 + threadIdx.x)*4;
    float4 v = *(const float4*)(W+i);
    ushort4 o;
    o.x = __builtin_bit_cast(u16, (_Float16)v.x);
    o.y = __builtin_bit_cast(u16, (_Float16)v.y);
    o.z = __builtin_bit_cast(u16, (_Float16)v.z);
    o.w = __builtin_bit_cast(u16, (_Float16)v.w);
    *(ushort4*)(P+i) = o;
}

// Persistent encoder: W-fragments in REGISTERS, A-fragments global->VGPR direct
// (relaxed agent loads, IF$-coherent), LDS only for the Cp cross-wave reduction.
// Block b: batch-tile (b&7) x d-tile (b>>3). Sync: one counter per batch-tile,
// producer relaxed fetch_add after __syncthreads drain; tid0 polls.
__global__ __launch_bounds__(512, 1) void lstm_persist(
    const u16* __restrict__ Wh,           // [2048][512] fp16
    const float* __restrict__ bih, const float* __restrict__ bhh,
    const float* __restrict__ Wih, const float* __restrict__ x,
    u16* __restrict__ hp0, u16* __restrict__ hp1,   // [512][512] fp16
    float* __restrict__ c, float* __restrict__ dbase,
    u32* __restrict__ ctr)
{
    const int tid  = threadIdx.x;
    const int lane = tid & 63;
    const int wave = tid >> 6;
    const int kh = wave >> 2;           // K-half (256 k each)
    const int rq = (wave >> 1) & 1;     // batch-row quadrant
    const int cq = wave & 1;            // col quadrant

    const int gb = blockIdx.x & 7;
    const int dt = blockIdx.x >> 3;
    const int b0 = gb*64, d0 = dt*16;
    u32* cnt = ctr + gb*32;             // one counter per group, 128 B apart

    __shared__ __align__(16) float Cp[2*CPH];   // 33280 B

    const int la = lane & 31;
    const int hi = lane >> 5;

    // ---- W fragments -> registers (once; W immutable across steps) ----
    const int colb = cq*32 + la;                          // 0..63
    const size_t wrow = (size_t)((colb >> 4)*HID + d0 + (colb & 15));
    const u16* wp = Wh + wrow*HID + kh*256 + hi*8;
    half8 wreg[16];
#pragma unroll
    for (int m = 0; m < 16; ++m)
        wreg[m] = __builtin_bit_cast(half8, *(const uint4*)(wp + m*16));

    // ---- A fragment base (elements): row b0+ra, k = kh*256 + m*16 + hi*8 ----
    const int ra = rq*32 + la;
    const size_t abase = (size_t)(b0 + ra)*HID + kh*256 + hi*8;
    const u64* pA0 = (const u64*)(hp0 + abase);
    const u64* pA1 = (const u64*)(hp1 + abase);

    // ---- epilogue constants ----
    const int bl  = tid >> 3;
    const int eb  = b0 + bl;
    const int dl0 = (tid & 7) * 2;
    float CB[2][4], WV[2][4];
#pragma unroll
    for (int j = 0; j < 2; ++j){
        const int d = d0 + dl0 + j;
#pragma unroll
        for (int q = 0; q < 4; ++q){
            CB[j][q] = bih[q*HID + d] + bhh[q*HID + d];
            WV[j][q] = Wih[q*HID + d];
        }
    }
    float creg[2] = {0.f, 0.f};
    const float* xrow = x + (size_t)eb*TSEQ;

    for (int t = 0; t <= TSEQ; ++t){
        if (t > 0){
            if (tid == 0){
                const u32 tgt = 32u * (u32)t;
                while (__hip_atomic_load(cnt, __ATOMIC_RELAXED, __HIP_MEMORY_SCOPE_AGENT) < tgt)
                    __builtin_amdgcn_s_sleep(1);
            }
            __syncthreads();            // release block; also fences prev Cp reads
        }
        const u64* pA = (t & 1) ? pA1 : pA0;
        u16*       hd = (t & 1) ? hp0 : hp1;

        // ---- issue all 32 A-loads (IF$-coherent), then MFMA chain ----
        // sub-tile m covers k = m*16 halves = m*4 u64s
        u64 a0[16], a1[16];
#pragma unroll
        for (int m = 0; m < 16; ++m){
            a0[m] = __hip_atomic_load(pA + m*4,     __ATOMIC_RELAXED, __HIP_MEMORY_SCOPE_AGENT);
            a1[m] = __hip_atomic_load(pA + m*4 + 1, __ATOMIC_RELAXED, __HIP_MEMORY_SCOPE_AGENT);
        }
        f32x16 accA = {}, accB = {};
#pragma unroll
        for (int m = 0; m < 16; m += 2){
            u64x2 qa; qa[0] = a0[m];   qa[1] = a1[m];
            u64x2 qb; qb[0] = a0[m+1]; qb[1] = a1[m+1];
            accA = __builtin_amdgcn_mfma_f32_32x32x16_f16(__builtin_bit_cast(half8, qa), wreg[m],   accA, 0,0,0);
            accB = __builtin_amdgcn_mfma_f32_32x32x16_f16(__builtin_bit_cast(half8, qb), wreg[m+1], accB, 0,0,0);
        }

        // ---- K-partials -> Cp[kh][64][65] ----
#pragma unroll
        for (int r = 0; r < 16; ++r){
            const int crow = (r & 3) + 8*(r >> 2) + 4*hi;
            Cp[kh*CPH + (rq*32 + crow)*CPS + cq*32 + la] = accA[r] + accB[r];
        }
        __syncthreads();

        if (t < TSEQ){
            const float xv = xrow[t];
            u16 hbits[2];
#pragma unroll
            for (int j = 0; j < 2; ++j){
                const int dl = dl0 + j;
                const float g0 = Cp[bl*CPS + dl]      + Cp[CPH + bl*CPS + dl]      + CB[j][0] + xv*WV[j][0];
                const float g1 = Cp[bl*CPS + 16 + dl] + Cp[CPH + bl*CPS + 16 + dl] + CB[j][1] + xv*WV[j][1];
                const float g2 = Cp[bl*CPS + 32 + dl] + Cp[CPH + bl*CPS + 32 + dl] + CB[j][2] + xv*WV[j][2];
                const float g3 = Cp[bl*CPS + 48 + dl] + Cp[CPH + bl*CPS + 48 + dl] + CB[j][3] + xv*WV[j][3];
                const float cn = sigf(g1)*creg[j] + sigf(g0)*tanhf_fast(g2);
                const float hn = sigf(g3)*tanhf_fast(cn);
                creg[j] = cn;
                hbits[j] = __builtin_bit_cast(u16, (_Float16)hn);
            }
            const u32 pk = (u32)hbits[0] | ((u32)hbits[1] << 16);
            __hip_atomic_store((u32*)(hd + (size_t)eb*HID + d0 + dl0), pk,
                               __ATOMIC_RELAXED, __HIP_MEMORY_SCOPE_AGENT);
            if (t == TSEQ-1){
                c[eb*HID + d0 + dl0]     = creg[0];
                c[eb*HID + d0 + dl0 + 1] = creg[1];
            }
            __syncthreads();            // drain vmcnt: h stores IF$-visible, Cp reads done
            if (tid == 0)
                __hip_atomic_fetch_add(cnt, 1u, __ATOMIC_RELAXED, __HIP_MEMORY_SCOPE_AGENT);
        } else {
#pragma unroll
            for (int j = 0; j < 2; ++j){
                const int dl = dl0 + j;
                const int d  = d0 + dl;
                dbase[eb*G4 + d]         = Cp[bl*CPS + dl]      + Cp[CPH + bl*CPS + dl]      + CB[j][0];
                dbase[eb*G4 + HID + d]   = Cp[bl*CPS + 16 + dl] + Cp[CPH + bl*CPS + 16 + dl] + CB[j][1];
                dbase[eb*G4 + 2*HID + d] = Cp[bl*CPS + 32 + dl] + Cp[CPH + bl*CPS + 32 + dl] + CB[j][2];
                dbase[eb*G4 + 3*HID + d] = Cp[bl*CPS + 48 + dl] + Cp[CPH + bl*CPS + 48 + dl] + CB[j][3];
            }
        }
    }
}

// Decoder: hidden/cell frozen, dec_base precomputed. One block per batch row.
__global__ __launch_bounds__(256) void lstm_dec(
    const u16* __restrict__ hp, const float* __restrict__ dbase,
    const float* __restrict__ cell, const float* __restrict__ Wih,
    const float* __restrict__ Wout, const float* __restrict__ bout,
    float* __restrict__ out)
{
    const int b   = blockIdx.x;
    const int tid = threadIdx.x;
    __shared__ float red[8];

    const int dA = tid, dB = tid + 256;
    const float woA = Wout[dA], woB = Wout[dB];
    float hA = (float)__builtin_bit_cast(_Float16, hp[b*HID + dA]);
    float hB = (float)__builtin_bit_cast(_Float16, hp[b*HID + dB]);
    const float cA = cell[b*HID + dA], cB = cell[b*HID + dB];
    const float biA = dbase[b*G4 + dA],          biB = dbase[b*G4 + dB];
    const float bfA = dbase[b*G4 + HID + dA],    bfB = dbase[b*G4 + HID + dB];
    const float bgA = dbase[b*G4 + 2*HID + dA],  bgB = dbase[b*G4 + 2*HID + dB];
    const float boA = dbase[b*G4 + 3*HID + dA],  boB = dbase[b*G4 + 3*HID + dB];
    const float wiA = Wih[dA],          wiB = Wih[dB];
    const float wfA = Wih[HID + dA],    wfB = Wih[HID + dB];
    const float wgA = Wih[2*HID + dA],  wgB = Wih[2*HID + dB];
    const float wxA = Wih[3*HID + dA],  wxB = Wih[3*HID + dB];
    const float bo  = bout[0];

    for (int s = 0; s < DECSTEPS; ++s) {
        float p = hA * woA + hB * woB;
#pragma unroll
        for (int m = 1; m < 64; m <<= 1) p += __shfl_xor(p, m, 64);
        if ((tid & 63) == 0) red[tid >> 6] = p;
        __syncthreads();
        const float ov = red[0] + red[1] + red[2] + red[3] + bo;
        if (tid == 0) out[b * DECSTEPS + s] = ov;
        __syncthreads();

        {
            const float gi = sigf(__builtin_fmaf(ov, wiA, biA));
            const float gf = sigf(__builtin_fmaf(ov, wfA, bfA));
            const float gg = tanhf(__builtin_fmaf(ov, wgA, bgA));
            const float go = sigf(__builtin_fmaf(ov, wxA, boA));
            hA = go * tanhf(gf * cA + gi * gg);
        }
        {
            const float gi = sigf(__builtin_fmaf(ov, wiB, biB));
            const float gf = sigf(__builtin_fmaf(ov, wfB, bfB));
            const float gg = tanhf(__builtin_fmaf(ov, wgB, bgB));
            const float go = sigf(__builtin_fmaf(ov, wxB, boB));
            hB = go * tanhf(gf * cB + gi * gg);
        }
    }
}

extern "C" void kernel_launch(void* const* d_in, const int* in_sizes, int n_in,
                              void* d_out, int out_size, void* d_ws, size_t ws_size,
                              hipStream_t stream) {
    const float* x    = (const float*)d_in[0];
    const float* Wih  = (const float*)d_in[1];
    const float* Whh  = (const float*)d_in[2];
    const float* bih  = (const float*)d_in[3];
    const float* bhh  = (const float*)d_in[4];
    const float* Wout = (const float*)d_in[5];
    const float* bout = (const float*)d_in[6];
    float* out = (float*)d_out;

    char* ws = (char*)d_ws;
    float* c     = (float*)(ws);                    // 1 MB
    float* dbase = (float*)(ws + (1u<<20));         // 4 MB
    u16*   Wh    = (u16*)  (ws + 5u*(1u<<20));      // 2 MB fp16 plane
    u16*   hp0   = (u16*)  (ws + 7u*(1u<<20));      // 512 KB
    u16*   hp1   = (u16*)  (ws + 7u*(1u<<20) + (1u<<19));
    u32*   ctr   = (u32*)  (ws + 8u*(1u<<20));      // 8 counters, 128 B apart

    hipMemsetAsync(hp0, 0, (1u<<19), stream);       // h(0) = 0
    hipMemsetAsync(ctr, 0, 4096, stream);
    pack_w<<<dim3(1024), dim3(256), 0, stream>>>(Whh, Wh);

    lstm_persist<<<dim3(256), dim3(512), 0, stream>>>(
        Wh, bih, bhh, Wih, x, hp0, hp1, c, dbase, ctr);

    lstm_dec<<<dim3(BATCH), dim3(256), 0, stream>>>(hp0, dbase, c, Wih, Wout, bout, out);
}